// Round 7
// baseline (174.651 us; speedup 1.0000x reference)
//
#include <hip/hip_runtime.h>

#define N_NODES 8192
#define DIM     128
#define N_COMM  100
#define MARGIN  1.0f

// pos kernel LDS tiling (measured conflict-free)
#define LDS_STRP 72

typedef __attribute__((ext_vector_type(8)))  short bf16x8;
typedef __attribute__((ext_vector_type(16))) float f32x16;

__device__ inline unsigned short f32_to_bf16_rne(float f) {
    unsigned u = __float_as_uint(f);
    unsigned r = u + 0x7fffu + ((u >> 16) & 1u);
    return (unsigned short)(r >> 16);
}
__device__ inline float bf16_to_f32(unsigned short h) {
    return __uint_as_float(((unsigned)h) << 16);
}

// ---------------------------------------------------------------------------
// Kernel 0: bf16 hi/lo split + row sq norms + min_d2 init. Wave per row.
__global__ __launch_bounds__(256)
void prep_kernel(const float* __restrict__ x,
                 unsigned short* __restrict__ xhi,
                 unsigned short* __restrict__ xlo,
                 float* __restrict__ sq,
                 unsigned int* __restrict__ min_d2) {
    int row  = blockIdx.x * 4 + (threadIdx.x >> 6);
    int lane = threadIdx.x & 63;
    const float* p = x + (size_t)row * DIM;
    float v0 = p[lane], v1 = p[lane + 64];
    unsigned short h0 = f32_to_bf16_rne(v0), h1 = f32_to_bf16_rne(v1);
    unsigned short l0 = f32_to_bf16_rne(v0 - bf16_to_f32(h0));
    unsigned short l1 = f32_to_bf16_rne(v1 - bf16_to_f32(h1));
    size_t base = (size_t)row * DIM;
    xhi[base + lane] = h0;  xhi[base + 64 + lane] = h1;
    xlo[base + lane] = l0;  xlo[base + 64 + lane] = l1;
    float s = v0 * v0 + v1 * v1;
    #pragma unroll
    for (int off = 32; off > 0; off >>= 1) s += __shfl_down(s, off);
    if (lane == 0) {
        sq[row] = s;
        min_d2[row] = 0x7f800000u;   // +inf bits
    }
}

// ---------------------------------------------------------------------------
// Kernel 0b: counts + prefix (1 small block; coalesced reads, LDS atomics).
__global__ __launch_bounds__(256)
void scan_kernel(const int* __restrict__ comm,
                 int* __restrict__ offs,   // [N_COMM+1]
                 int* __restrict__ cur) {  // [N_COMM] running cursors
    __shared__ int lcnt[N_COMM];
    const int tid = threadIdx.x;
    if (tid < N_COMM) lcnt[tid] = 0;
    __syncthreads();
    for (int i = tid; i < N_NODES; i += 256) atomicAdd(&lcnt[comm[i]], 1);
    __syncthreads();
    if (tid == 0) {
        int acc = 0;
        for (int c = 0; c < N_COMM; ++c) {
            offs[c] = acc; cur[c] = acc; acc += lcnt[c];
        }
        offs[N_COMM] = acc;
    }
}

// ---------------------------------------------------------------------------
// Kernel 0c: parallel scatter, LDS-aggregated block reservations (64 blocks).
// Order within a community is arbitrary (sums are order-independent).
__global__ __launch_bounds__(128)
void scatter_kernel(const int* __restrict__ comm,
                    int* __restrict__ cur,
                    int* __restrict__ members) {
    __shared__ int lcnt[N_COMM], lbase[N_COMM], lcur[N_COMM];
    const int tid = threadIdx.x;
    const int i   = blockIdx.x * 128 + tid;     // 64 blocks x 128 nodes
    if (tid < N_COMM) { lcnt[tid] = 0; lcur[tid] = 0; }
    __syncthreads();
    const int c = comm[i];
    atomicAdd(&lcnt[c], 1);
    __syncthreads();
    if (tid < N_COMM && lcnt[tid] > 0)
        lbase[tid] = atomicAdd(&cur[tid], lcnt[tid]);
    __syncthreads();
    int pos = lbase[c] + atomicAdd(&lcur[c], 1);
    members[pos] = i;
}

// ---------------------------------------------------------------------------
// Kernel 1 (v4): MFMA X·X^T (bf16 hi/lo), exact triangular grid, fragment-
// packed LDS (conflict-free, DMA-stageable), DOUBLE-BUFFERED global_load_lds:
// K in 8 chunks of 16; DMA for chunk k+1 issued right after the barrier that
// publishes chunk k, so its L2 latency is covered by chunk-k compute.
// LDS: 2 bufs x 4 tiles x 4 rowgroups x 64 lanes x 16 B = 32 KB (+overlay).
// C/D layout (m74/m101): col = lane&31, row = (reg&3) + 8*(reg>>2) + 4*(lane>>5).
__global__ __launch_bounds__(256, 4)
void minneg_mfma_kernel(const unsigned short* __restrict__ xhi,
                        const unsigned short* __restrict__ xlo,
                        const int* __restrict__ comm,
                        const float* __restrict__ sq,
                        unsigned int* __restrict__ min_d2) {
    __shared__ __align__(16) char smem[33792];      // max(32 KB dbuf, overlay)
    __shared__ unsigned int colmin[128];
    unsigned short (*frag)[4][4][64][8] =
        (unsigned short (*)[4][4][64][8])smem;      // [buf][tile][rg][lane][8]
    float (*rowpart)[66] = (float (*)[66])smem;     // epilogue overlay 33792 B

    // linear -> lower-triangle (bx >= by)
    const int b = blockIdx.x;
    int bx = (int)((sqrtf(8.f * (float)b + 1.f) - 1.f) * 0.5f);
    while ((bx + 1) * (bx + 2) / 2 <= b) ++bx;
    while (bx * (bx + 1) / 2 > b) --bx;
    const int by = b - bx * (bx + 1) / 2;

    const int tid  = threadIdx.x;
    const int lane = tid & 63;
    const int w    = tid >> 6;
    const int wr   = w >> 1, wc = w & 1;
    const int lr   = lane & 31;
    const int lh   = lane >> 5;
    const int i0   = bx * 128;      // A rows
    const int j0   = by * 128;      // B rows (= output cols)

    if (tid < 128) colmin[tid] = 0x7f800000u;

    // wave w stages tile w: 0=Ahi 1=Alo 2=Bhi 3=Blo.
    // lane l: row = rbase + rg*32 + (l&31), k = ck*16 + (l>>5)*8 .. +8
    const unsigned short* src   = (w & 1) ? xlo : xhi;
    const int             rbw   = ((w & 2) ? j0 : i0) + lr;
    const unsigned short* gbase = src + (size_t)rbw * DIM + lh * 8;

    f32x16 acc[2][2];
    #pragma unroll
    for (int g = 0; g < 2; ++g)
        #pragma unroll
        for (int h = 0; h < 2; ++h)
            #pragma unroll
            for (int e = 0; e < 16; ++e) acc[g][h][e] = 0.f;

    // prologue: chunk 0 -> buf 0
    #pragma unroll
    for (int rg = 0; rg < 4; ++rg)
        __builtin_amdgcn_global_load_lds(
            (const __attribute__((address_space(1))) void*)(gbase + rg * 32 * DIM),
            (__attribute__((address_space(3))) void*)&frag[0][w][rg][0][0],
            16, 0, 0);

    #pragma unroll
    for (int ck = 0; ck < 8; ++ck) {
        __syncthreads();   // publishes chunk ck (vmcnt drain covered by ck-1 compute)
        const int p = ck & 1;
        if (ck < 7) {      // prefetch chunk ck+1 into the other buffer
            #pragma unroll
            for (int rg = 0; rg < 4; ++rg)
                __builtin_amdgcn_global_load_lds(
                    (const __attribute__((address_space(1))) void*)
                        (gbase + (ck + 1) * 16 + rg * 32 * DIM),
                    (__attribute__((address_space(3))) void*)&frag[1 - p][w][rg][0][0],
                    16, 0, 0);
        }

        bf16x8 ahi[2], bhi[2];
        #pragma unroll
        for (int g = 0; g < 2; ++g)
            ahi[g] = *(const bf16x8*)&frag[p][0][wr * 2 + g][lane][0];
        #pragma unroll
        for (int h = 0; h < 2; ++h)
            bhi[h] = *(const bf16x8*)&frag[p][2][wc * 2 + h][lane][0];
        #pragma unroll
        for (int g = 0; g < 2; ++g)
            #pragma unroll
            for (int h = 0; h < 2; ++h)
                acc[g][h] = __builtin_amdgcn_mfma_f32_32x32x16_bf16(
                    ahi[g], bhi[h], acc[g][h], 0, 0, 0);
        {
            bf16x8 alo[2];
            #pragma unroll
            for (int g = 0; g < 2; ++g)
                alo[g] = *(const bf16x8*)&frag[p][1][wr * 2 + g][lane][0];
            #pragma unroll
            for (int g = 0; g < 2; ++g)
                #pragma unroll
                for (int h = 0; h < 2; ++h)
                    acc[g][h] = __builtin_amdgcn_mfma_f32_32x32x16_bf16(
                        alo[g], bhi[h], acc[g][h], 0, 0, 0);
        }
        {
            bf16x8 blo[2];
            #pragma unroll
            for (int h = 0; h < 2; ++h)
                blo[h] = *(const bf16x8*)&frag[p][3][wc * 2 + h][lane][0];
            #pragma unroll
            for (int g = 0; g < 2; ++g)
                #pragma unroll
                for (int h = 0; h < 2; ++h)
                    acc[g][h] = __builtin_amdgcn_mfma_f32_32x32x16_bf16(
                        ahi[g], blo[h], acc[g][h], 0, 0, 0);
        }
    }

    // ---- epilogue: d2 = sq_i + sq_j - 2*dot ; col-min AND row-min over negatives
    int   civ[2][4][4];
    float sqv[2][4][4];
    #pragma unroll
    for (int g = 0; g < 2; ++g)
        #pragma unroll
        for (int q = 0; q < 4; ++q) {
            int rb = i0 + wr * 64 + g * 32 + 4 * lh + 8 * q;
            *(int4*)&civ[g][q][0]   = *(const int4*)&comm[rb];
            *(float4*)&sqv[g][q][0] = *(const float4*)&sq[rb];
        }

    const float FINF = __uint_as_float(0x7f800000u);
    float rmin[2][16];
    #pragma unroll
    for (int g = 0; g < 2; ++g)
        #pragma unroll
        for (int e = 0; e < 16; ++e) rmin[g][e] = FINF;

    #pragma unroll
    for (int h = 0; h < 2; ++h) {
        int colt = wc * 64 + h * 32 + lr;
        int j  = j0 + colt;
        int cj = comm[j];
        float sqj = sq[j];
        float cmin = FINF;
        #pragma unroll
        for (int g = 0; g < 2; ++g)
            #pragma unroll
            for (int q = 0; q < 4; ++q)
                #pragma unroll
                for (int t = 0; t < 4; ++t) {
                    float d2 = fmaxf(sqv[g][q][t] + sqj - 2.f * acc[g][h][q * 4 + t], 0.f);
                    if (civ[g][q][t] != cj) {
                        cmin = fminf(cmin, d2);
                        rmin[g][q * 4 + t] = fminf(rmin[g][q * 4 + t], d2);
                    }
                }
        cmin = fminf(cmin, __shfl_xor(cmin, 32));
        if (lh == 0) atomicMin(&colmin[colt], __float_as_uint(cmin));
    }

    // row-min: scatter partials into LDS overlay, 128-thread reduce
    __syncthreads();                           // all fragment reads of frag done
    #pragma unroll
    for (int g = 0; g < 2; ++g)
        #pragma unroll
        for (int q = 0; q < 4; ++q)
            #pragma unroll
            for (int t = 0; t < 4; ++t) {
                int rowl = wr * 64 + g * 32 + 4 * lh + 8 * q + t;
                rowpart[rowl][wc * 32 + lr] = rmin[g][q * 4 + t];
            }
    __syncthreads();
    if (tid < 128) {
        float m = FINF;
        #pragma unroll
        for (int k = 0; k < 16; ++k) {
            float4 v = *(const float4*)&rowpart[tid][k * 4];
            m = fminf(m, fminf(fminf(v.x, v.y), fminf(v.z, v.w)));
        }
        atomicMin(&min_d2[i0 + tid], __float_as_uint(m));
        atomicMin(&min_d2[j0 + tid], colmin[tid]);
    }
}

// ---------------------------------------------------------------------------
// Kernel 2: positives via community-gathered MFMA Gram, one block/community,
// wave-uniform subtile guards. (unchanged — conflict-free stride 72)
__global__ __launch_bounds__(256, 2)
void pos_mfma_kernel(const unsigned short* __restrict__ xhi,
                     const unsigned short* __restrict__ xlo,
                     const float* __restrict__ sq,
                     const unsigned int* __restrict__ min_d2,
                     const int* __restrict__ offs,
                     const int* __restrict__ members,
                     double* __restrict__ psum,
                     unsigned int* __restrict__ pcnt) {
    __shared__ __align__(16) unsigned short lds[4][128][LDS_STRP];  // 72 KB
    __shared__ float sqA[128], sqB[128], mnA[128];
    __shared__ double sred[4];
    __shared__ unsigned int cred[4];

    const int tid  = threadIdx.x;
    const int lane = tid & 63;
    const int w    = tid >> 6;
    const int wr   = w >> 1, wc = w & 1;
    const int lr   = lane & 31;
    const int lh   = lane >> 5;

    const int c    = blockIdx.x;
    const int beg  = offs[c], end = offs[c + 1];
    const int size = end - beg;
    const int nt   = (size + 127) >> 7;

    float tsum = 0.f;
    unsigned int tcnt = 0u;

    for (int tr = 0; tr < nt; ++tr)
    for (int tc = 0; tc < nt; ++tc) {
        bool av[2], bv[2];
        #pragma unroll
        for (int g = 0; g < 2; ++g) av[g] = (tr * 128 + wr * 64 + g * 32) < size;
        #pragma unroll
        for (int h = 0; h < 2; ++h) bv[h] = (tc * 128 + wc * 64 + h * 32) < size;

        __syncthreads();
        if (tid < 128) {
            int ii = beg + tr * 128 + tid;
            if (ii < end) {
                int ia = members[ii];
                sqA[tid] = sq[ia];
                unsigned int mb = min_d2[ia];
                mnA[tid] = (mb == 0x7f800000u) ? -1.f
                         : sqrtf(fmaxf(__uint_as_float(mb), 0.f));
            } else { sqA[tid] = 0.f; mnA[tid] = -1.f; }
        } else {
            int t2 = tid - 128;
            int jj = beg + tc * 128 + t2;
            sqB[t2] = (jj < end) ? sq[members[jj]] : 0.f;
        }

        f32x16 acc[2][2];
        #pragma unroll
        for (int g = 0; g < 2; ++g)
            #pragma unroll
            for (int h = 0; h < 2; ++h)
                #pragma unroll
                for (int e = 0; e < 16; ++e) acc[g][h][e] = 0.f;

        for (int kh = 0; kh < 2; ++kh) {
            __syncthreads();
            #pragma unroll
            for (int it = 0; it < 16; ++it) {
                int g    = tid + it * 256;
                int tile = g >> 10;
                int row  = (g >> 3) & 127;
                int seg  = g & 7;
                int mi   = beg + ((tile & 2) ? tc : tr) * 128 + row;
                int node = (mi < end) ? members[mi] : 0;
                const unsigned short* src = (tile & 1) ? xlo : xhi;
                uint4 v = *(const uint4*)&src[(size_t)node * DIM + kh * 64 + seg * 8];
                *(uint4*)&lds[tile][row][seg * 8] = v;
            }
            __syncthreads();

            #pragma unroll
            for (int ks = 0; ks < 4; ++ks) {
                const int kb = ks * 16 + lh * 8;
                bf16x8 ahi[2], alo[2], bhi[2], blo[2];
                #pragma unroll
                for (int g = 0; g < 2; ++g) if (av[g]) {
                    ahi[g] = *(const bf16x8*)&lds[0][wr * 64 + g * 32 + lr][kb];
                    alo[g] = *(const bf16x8*)&lds[1][wr * 64 + g * 32 + lr][kb];
                }
                #pragma unroll
                for (int h = 0; h < 2; ++h) if (bv[h]) {
                    bhi[h] = *(const bf16x8*)&lds[2][wc * 64 + h * 32 + lr][kb];
                    blo[h] = *(const bf16x8*)&lds[3][wc * 64 + h * 32 + lr][kb];
                }
                #pragma unroll
                for (int g = 0; g < 2; ++g)
                    #pragma unroll
                    for (int h = 0; h < 2; ++h) if (av[g] && bv[h]) {
                        acc[g][h] = __builtin_amdgcn_mfma_f32_32x32x16_bf16(
                            ahi[g], bhi[h], acc[g][h], 0, 0, 0);
                        acc[g][h] = __builtin_amdgcn_mfma_f32_32x32x16_bf16(
                            ahi[g], blo[h], acc[g][h], 0, 0, 0);
                        acc[g][h] = __builtin_amdgcn_mfma_f32_32x32x16_bf16(
                            alo[g], bhi[h], acc[g][h], 0, 0, 0);
                    }
            }
        }

        #pragma unroll
        for (int h = 0; h < 2; ++h) {
            if (!bv[h]) continue;
            int coll = wc * 64 + h * 32 + lr;
            int jv   = tc * 128 + coll;
            float sqj = sqB[coll];
            #pragma unroll
            for (int g = 0; g < 2; ++g) {
                if (!av[g]) continue;
                #pragma unroll
                for (int q = 0; q < 4; ++q)
                    #pragma unroll
                    for (int t = 0; t < 4; ++t) {
                        int rowl = wr * 64 + g * 32 + 4 * lh + 8 * q + t;
                        int iv   = tr * 128 + rowl;
                        float mn = mnA[rowl];
                        if (iv < size && jv < size && iv != jv && mn >= 0.f) {
                            float d2 = sqA[rowl] + sqj - 2.f * acc[g][h][q * 4 + t];
                            float dist = sqrtf(fmaxf(d2, 0.f));
                            tsum += fmaxf(dist - mn + MARGIN, 0.f);
                            tcnt += 1u;
                        }
                    }
            }
        }
    }

    #pragma unroll
    for (int off = 32; off > 0; off >>= 1) {
        tsum += __shfl_down(tsum, off);
        tcnt += __shfl_down(tcnt, off);
    }
    if (lane == 0) { sred[w] = (double)tsum; cred[w] = tcnt; }
    __syncthreads();
    if (tid == 0) {
        psum[c] = sred[0] + sred[1] + sred[2] + sred[3];
        pcnt[c] = cred[0] + cred[1] + cred[2] + cred[3];
    }
}

// ---------------------------------------------------------------------------
// Kernel 3: reduce 100 community partials -> final mean.
__global__ __launch_bounds__(256)
void finalize_kernel(const double* __restrict__ psum,
                     const unsigned int* __restrict__ pcnt,
                     float* __restrict__ out) {
    __shared__ double       ds[256];
    __shared__ unsigned int cs[256];
    const int t = threadIdx.x;
    double s = 0.0; unsigned int c = 0u;
    for (int b = t; b < N_COMM; b += 256) { s += psum[b]; c += pcnt[b]; }
    ds[t] = s; cs[t] = c;
    __syncthreads();
    for (int off = 128; off > 0; off >>= 1) {
        if (t < off) { ds[t] += ds[t + off]; cs[t] += cs[t + off]; }
        __syncthreads();
    }
    if (t == 0) out[0] = (cs[0] > 0u) ? (float)(ds[0] / (double)cs[0]) : 0.f;
}

// ---------------------------------------------------------------------------
extern "C" void kernel_launch(void* const* d_in, const int* in_sizes, int n_in,
                              void* d_out, int out_size, void* d_ws, size_t ws_size,
                              hipStream_t stream) {
    const float* x    = (const float*)d_in[0];
    const int*   comm = (const int*)d_in[1];
    float*       out  = (float*)d_out;

    // workspace layout (bytes):
    //       0 float  sq[8192]           32768
    //   32768 uint   min_d2[8192]       32768
    //   65536 int    offs[101]            512 (padded)
    //   66048 int    cur[100]             512 (padded)
    //   66560 int    members[8192]      32768
    //   99328 double psum[100]           1024 (padded)
    //  100352 uint   pcnt[100]            512 (padded)
    //  100864 ushort xhi[8192*128]    2097152
    // 2198016 ushort xlo[8192*128]    2097152   (total ~4.1 MB)
    char* ws = (char*)d_ws;
    float*          sq      = (float*)(ws);
    unsigned int*   min_d2  = (unsigned int*)(ws + 32768);
    int*            offs    = (int*)(ws + 65536);
    int*            cur     = (int*)(ws + 66048);
    int*            members = (int*)(ws + 66560);
    double*         psum    = (double*)(ws + 99328);
    unsigned int*   pcnt    = (unsigned int*)(ws + 100352);
    unsigned short* xhi     = (unsigned short*)(ws + 100864);
    unsigned short* xlo     = (unsigned short*)(ws + 2198016);

    prep_kernel<<<2048, 256, 0, stream>>>(x, xhi, xlo, sq, min_d2);

    scan_kernel<<<1, 256, 0, stream>>>(comm, offs, cur);

    scatter_kernel<<<64, 128, 0, stream>>>(comm, cur, members);

    const int ntri = (N_NODES / 128) * (N_NODES / 128 + 1) / 2;   // 2080
    minneg_mfma_kernel<<<ntri, 256, 0, stream>>>(xhi, xlo, comm, sq, min_d2);

    pos_mfma_kernel<<<N_COMM, 256, 0, stream>>>(xhi, xlo, sq, min_d2, offs, members,
                                                psum, pcnt);

    finalize_kernel<<<1, 256, 0, stream>>>(psum, pcnt, out);
}

// Round 10
// 163.711 us; speedup vs baseline: 1.0668x; 1.0668x over previous
//
#include <hip/hip_runtime.h>

#define N_NODES 8192
#define DIM     128
#define N_COMM  100
#define MARGIN  1.0f

// pos kernel LDS tiling (measured conflict-free)
#define LDS_STRP 72

typedef __attribute__((ext_vector_type(8)))  short bf16x8;
typedef __attribute__((ext_vector_type(16))) float f32x16;

__device__ inline unsigned short f32_to_bf16_rne(float f) {
    unsigned u = __float_as_uint(f);
    unsigned r = u + 0x7fffu + ((u >> 16) & 1u);
    return (unsigned short)(r >> 16);
}
__device__ inline float bf16_to_f32(unsigned short h) {
    return __uint_as_float(((unsigned)h) << 16);
}

// ---------------------------------------------------------------------------
// Kernel 0: blocks 0..2047: bf16 hi/lo split + row sq norms + min_d2 init
// (wave per row). Blocks 2048..2147: community c = bid-2048 histograms comm
// in LDS, derives its own offset, scatters its own member segment.
__global__ __launch_bounds__(256)
void prep_kernel(const float* __restrict__ x,
                 const int* __restrict__ comm,
                 unsigned short* __restrict__ xhi,
                 unsigned short* __restrict__ xlo,
                 float* __restrict__ sq,
                 unsigned int* __restrict__ min_d2,
                 int* __restrict__ offs,
                 int* __restrict__ members) {
    const int tid = threadIdx.x;

    if (blockIdx.x < 2048) {
        int row  = blockIdx.x * 4 + (tid >> 6);
        int lane = tid & 63;
        const float* p = x + (size_t)row * DIM;
        float v0 = p[lane], v1 = p[lane + 64];
        unsigned short h0 = f32_to_bf16_rne(v0), h1 = f32_to_bf16_rne(v1);
        unsigned short l0 = f32_to_bf16_rne(v0 - bf16_to_f32(h0));
        unsigned short l1 = f32_to_bf16_rne(v1 - bf16_to_f32(h1));
        size_t base = (size_t)row * DIM;
        xhi[base + lane] = h0;  xhi[base + 64 + lane] = h1;
        xlo[base + lane] = l0;  xlo[base + 64 + lane] = l1;
        float s = v0 * v0 + v1 * v1;
        #pragma unroll
        for (int off = 32; off > 0; off >>= 1) s += __shfl_down(s, off);
        if (lane == 0) {
            sq[row] = s;
            min_d2[row] = 0x7f800000u;   // +inf bits
        }
        return;
    }

    // ---- bucketing: one block per community
    __shared__ int hist[N_COMM];
    __shared__ int cursor;
    const int c = blockIdx.x - 2048;
    if (tid < N_COMM) hist[tid] = 0;
    __syncthreads();
    for (int i = tid; i < N_NODES; i += 256) atomicAdd(&hist[comm[i]], 1);
    __syncthreads();
    if (tid == 0) {
        int acc = 0, base = 0;
        for (int cc = 0; cc < N_COMM; ++cc) {
            if (cc == c) base = acc;
            acc += hist[cc];
        }
        offs[c] = base;
        if (c == N_COMM - 1) offs[N_COMM] = acc;
        cursor = base;
    }
    __syncthreads();
    for (int i = tid; i < N_NODES; i += 256) {
        if (comm[i] == c) {
            int p = atomicAdd(&cursor, 1);
            members[p] = i;
        }
    }
}

// ---------------------------------------------------------------------------
// Kernel 1 (v5): MFMA X·X^T (bf16 hi/lo), exact triangular grid.
// A (this block's 128 rows, full K=128, hi+lo) lives in REGISTERS per wave
// (32 bf16x8 = 128 VGPRs). B (128 rows, full K, hi+lo) staged ONCE into
// fragment-packed LDS (64 KB) via global_load_lds. ONE barrier per block,
// then 96 uninterrupted MFMAs per wave.
// C/D layout (m74/m101): col = lane&31, row = (reg&3) + 8*(reg>>2) + 4*(lane>>5).
// A/B operand layout: m(n) = lane&31, k = (lane>>5)*8 + j.
__global__ __launch_bounds__(256, 2)
void minneg_mfma_kernel(const unsigned short* __restrict__ xhi,
                        const unsigned short* __restrict__ xlo,
                        const int* __restrict__ comm,
                        const float* __restrict__ sq,
                        unsigned int* __restrict__ min_d2) {
    __shared__ __align__(16) char smem[65536];     // bfrag / epilogue overlay
    __shared__ unsigned int colmin[128];
    // bfrag[hl][rg][ks][lane][8]: hl=hi/lo, rg=32-row group, ks=16-k chunk
    unsigned short (*bfrag)[4][8][64][8] =
        (unsigned short (*)[4][8][64][8])smem;
    float (*rowpart)[66] = (float (*)[66])smem;    // epilogue overlay 33792 B

    // linear -> lower-triangle (bx >= by)
    const int b = blockIdx.x;
    int bx = (int)((sqrtf(8.f * (float)b + 1.f) - 1.f) * 0.5f);
    while ((bx + 1) * (bx + 2) / 2 <= b) ++bx;
    while (bx * (bx + 1) / 2 > b) --bx;
    const int by = b - bx * (bx + 1) / 2;

    const int tid  = threadIdx.x;
    const int lane = tid & 63;
    const int w    = tid >> 6;
    const int wr   = w >> 1, wc = w & 1;
    const int lr   = lane & 31;
    const int lh   = lane >> 5;
    const int i0   = bx * 128;      // A rows
    const int j0   = by * 128;      // B rows (= output cols)

    if (tid < 128) colmin[tid] = 0x7f800000u;

    // ---- B staging: 8 packs (hl,rg), wave w stages packs 2w and 2w+1.
    // lane l supplies row j0 + rg*32 + (l&31), k-chunk [(l>>5)*8 .. +8) of
    // each 16-k slice; DMA dst = wave-uniform base + lane*16.
    #pragma unroll
    for (int pp = 0; pp < 2; ++pp) {
        const int p  = w * 2 + pp;
        const int hl = p >> 2, rg = p & 3;
        const unsigned short* src = hl ? xlo : xhi;
        const unsigned short* g0  = src + (size_t)(j0 + rg * 32 + lr) * DIM + lh * 8;
        #pragma unroll
        for (int ks = 0; ks < 8; ++ks)
            __builtin_amdgcn_global_load_lds(
                (const __attribute__((address_space(1))) void*)(g0 + ks * 16),
                (__attribute__((address_space(3))) void*)&bfrag[hl][rg][ks][0][0],
                16, 0, 0);
    }

    // ---- A registers: this wave's 64 rows (2 groups of 32), full K, hi+lo
    bf16x8 ahi[2][8], alo[2][8];
    #pragma unroll
    for (int g = 0; g < 2; ++g) {
        const size_t rbase = (size_t)(i0 + wr * 64 + g * 32 + lr) * DIM + lh * 8;
        #pragma unroll
        for (int ks = 0; ks < 8; ++ks) {
            ahi[g][ks] = *(const bf16x8*)&xhi[rbase + ks * 16];
            alo[g][ks] = *(const bf16x8*)&xlo[rbase + ks * 16];
        }
    }

    f32x16 acc[2][2];
    #pragma unroll
    for (int g = 0; g < 2; ++g)
        #pragma unroll
        for (int h = 0; h < 2; ++h)
            #pragma unroll
            for (int e = 0; e < 16; ++e) acc[g][h][e] = 0.f;

    __syncthreads();   // ONE barrier: B DMA drained, all packs published

    #pragma unroll
    for (int ks = 0; ks < 8; ++ks) {
        bf16x8 bhi[2], blo[2];
        #pragma unroll
        for (int h = 0; h < 2; ++h) {
            bhi[h] = *(const bf16x8*)&bfrag[0][wc * 2 + h][ks][lane][0];
            blo[h] = *(const bf16x8*)&bfrag[1][wc * 2 + h][ks][lane][0];
        }
        #pragma unroll
        for (int g = 0; g < 2; ++g)
            #pragma unroll
            for (int h = 0; h < 2; ++h) {
                acc[g][h] = __builtin_amdgcn_mfma_f32_32x32x16_bf16(
                    ahi[g][ks], bhi[h], acc[g][h], 0, 0, 0);
                acc[g][h] = __builtin_amdgcn_mfma_f32_32x32x16_bf16(
                    alo[g][ks], bhi[h], acc[g][h], 0, 0, 0);
                acc[g][h] = __builtin_amdgcn_mfma_f32_32x32x16_bf16(
                    ahi[g][ks], blo[h], acc[g][h], 0, 0, 0);
            }
    }

    // ---- epilogue: d2 = sq_i + sq_j - 2*dot ; col-min AND row-min over negatives
    int   civ[2][4][4];
    float sqv[2][4][4];
    #pragma unroll
    for (int g = 0; g < 2; ++g)
        #pragma unroll
        for (int q = 0; q < 4; ++q) {
            int rb = i0 + wr * 64 + g * 32 + 4 * lh + 8 * q;
            *(int4*)&civ[g][q][0]   = *(const int4*)&comm[rb];
            *(float4*)&sqv[g][q][0] = *(const float4*)&sq[rb];
        }

    const float FINF = __uint_as_float(0x7f800000u);
    float rmin[2][16];
    #pragma unroll
    for (int g = 0; g < 2; ++g)
        #pragma unroll
        for (int e = 0; e < 16; ++e) rmin[g][e] = FINF;

    #pragma unroll
    for (int h = 0; h < 2; ++h) {
        int colt = wc * 64 + h * 32 + lr;
        int j  = j0 + colt;
        int cj = comm[j];
        float sqj = sq[j];
        float cmin = FINF;
        #pragma unroll
        for (int g = 0; g < 2; ++g)
            #pragma unroll
            for (int q = 0; q < 4; ++q)
                #pragma unroll
                for (int t = 0; t < 4; ++t) {
                    float d2 = fmaxf(sqv[g][q][t] + sqj - 2.f * acc[g][h][q * 4 + t], 0.f);
                    if (civ[g][q][t] != cj) {
                        cmin = fminf(cmin, d2);
                        rmin[g][q * 4 + t] = fminf(rmin[g][q * 4 + t], d2);
                    }
                }
        cmin = fminf(cmin, __shfl_xor(cmin, 32));
        if (lh == 0) atomicMin(&colmin[colt], __float_as_uint(cmin));
    }

    // row-min: scatter partials into LDS overlay, 128-thread reduce
    __syncthreads();                           // all bfrag reads done
    #pragma unroll
    for (int g = 0; g < 2; ++g)
        #pragma unroll
        for (int q = 0; q < 4; ++q)
            #pragma unroll
            for (int t = 0; t < 4; ++t) {
                int rowl = wr * 64 + g * 32 + 4 * lh + 8 * q + t;
                rowpart[rowl][wc * 32 + lr] = rmin[g][q * 4 + t];
            }
    __syncthreads();
    if (tid < 128) {
        float m = FINF;
        #pragma unroll
        for (int k = 0; k < 16; ++k) {
            float4 v = *(const float4*)&rowpart[tid][k * 4];
            m = fminf(m, fminf(fminf(v.x, v.y), fminf(v.z, v.w)));
        }
        atomicMin(&min_d2[i0 + tid], __float_as_uint(m));
        atomicMin(&min_d2[j0 + tid], colmin[tid]);
    }
}

// ---------------------------------------------------------------------------
// Kernel 2: positives via community-gathered MFMA Gram, one block/community,
// wave-uniform subtile guards. (unchanged — conflict-free stride 72)
__global__ __launch_bounds__(256, 2)
void pos_mfma_kernel(const unsigned short* __restrict__ xhi,
                     const unsigned short* __restrict__ xlo,
                     const float* __restrict__ sq,
                     const unsigned int* __restrict__ min_d2,
                     const int* __restrict__ offs,
                     const int* __restrict__ members,
                     double* __restrict__ psum,
                     unsigned int* __restrict__ pcnt) {
    __shared__ __align__(16) unsigned short lds[4][128][LDS_STRP];  // 72 KB
    __shared__ float sqA[128], sqB[128], mnA[128];
    __shared__ double sred[4];
    __shared__ unsigned int cred[4];

    const int tid  = threadIdx.x;
    const int lane = tid & 63;
    const int w    = tid >> 6;
    const int wr   = w >> 1, wc = w & 1;
    const int lr   = lane & 31;
    const int lh   = lane >> 5;

    const int c    = blockIdx.x;
    const int beg  = offs[c], end = offs[c + 1];
    const int size = end - beg;
    const int nt   = (size + 127) >> 7;

    float tsum = 0.f;
    unsigned int tcnt = 0u;

    for (int tr = 0; tr < nt; ++tr)
    for (int tc = 0; tc < nt; ++tc) {
        bool av[2], bv[2];
        #pragma unroll
        for (int g = 0; g < 2; ++g) av[g] = (tr * 128 + wr * 64 + g * 32) < size;
        #pragma unroll
        for (int h = 0; h < 2; ++h) bv[h] = (tc * 128 + wc * 64 + h * 32) < size;

        __syncthreads();
        if (tid < 128) {
            int ii = beg + tr * 128 + tid;
            if (ii < end) {
                int ia = members[ii];
                sqA[tid] = sq[ia];
                unsigned int mb = min_d2[ia];
                mnA[tid] = (mb == 0x7f800000u) ? -1.f
                         : sqrtf(fmaxf(__uint_as_float(mb), 0.f));
            } else { sqA[tid] = 0.f; mnA[tid] = -1.f; }
        } else {
            int t2 = tid - 128;
            int jj = beg + tc * 128 + t2;
            sqB[t2] = (jj < end) ? sq[members[jj]] : 0.f;
        }

        f32x16 acc[2][2];
        #pragma unroll
        for (int g = 0; g < 2; ++g)
            #pragma unroll
            for (int h = 0; h < 2; ++h)
                #pragma unroll
                for (int e = 0; e < 16; ++e) acc[g][h][e] = 0.f;

        for (int kh = 0; kh < 2; ++kh) {
            __syncthreads();
            #pragma unroll
            for (int it = 0; it < 16; ++it) {
                int g    = tid + it * 256;
                int tile = g >> 10;
                int row  = (g >> 3) & 127;
                int seg  = g & 7;
                int mi   = beg + ((tile & 2) ? tc : tr) * 128 + row;
                int node = (mi < end) ? members[mi] : 0;
                const unsigned short* src = (tile & 1) ? xlo : xhi;
                uint4 v = *(const uint4*)&src[(size_t)node * DIM + kh * 64 + seg * 8];
                *(uint4*)&lds[tile][row][seg * 8] = v;
            }
            __syncthreads();

            #pragma unroll
            for (int ks = 0; ks < 4; ++ks) {
                const int kb = ks * 16 + lh * 8;
                bf16x8 ahi[2], alo[2], bhi[2], blo[2];
                #pragma unroll
                for (int g = 0; g < 2; ++g) if (av[g]) {
                    ahi[g] = *(const bf16x8*)&lds[0][wr * 64 + g * 32 + lr][kb];
                    alo[g] = *(const bf16x8*)&lds[1][wr * 64 + g * 32 + lr][kb];
                }
                #pragma unroll
                for (int h = 0; h < 2; ++h) if (bv[h]) {
                    bhi[h] = *(const bf16x8*)&lds[2][wc * 64 + h * 32 + lr][kb];
                    blo[h] = *(const bf16x8*)&lds[3][wc * 64 + h * 32 + lr][kb];
                }
                #pragma unroll
                for (int g = 0; g < 2; ++g)
                    #pragma unroll
                    for (int h = 0; h < 2; ++h) if (av[g] && bv[h]) {
                        acc[g][h] = __builtin_amdgcn_mfma_f32_32x32x16_bf16(
                            ahi[g], bhi[h], acc[g][h], 0, 0, 0);
                        acc[g][h] = __builtin_amdgcn_mfma_f32_32x32x16_bf16(
                            ahi[g], blo[h], acc[g][h], 0, 0, 0);
                        acc[g][h] = __builtin_amdgcn_mfma_f32_32x32x16_bf16(
                            alo[g], bhi[h], acc[g][h], 0, 0, 0);
                    }
            }
        }

        #pragma unroll
        for (int h = 0; h < 2; ++h) {
            if (!bv[h]) continue;
            int coll = wc * 64 + h * 32 + lr;
            int jv   = tc * 128 + coll;
            float sqj = sqB[coll];
            #pragma unroll
            for (int g = 0; g < 2; ++g) {
                if (!av[g]) continue;
                #pragma unroll
                for (int q = 0; q < 4; ++q)
                    #pragma unroll
                    for (int t = 0; t < 4; ++t) {
                        int rowl = wr * 64 + g * 32 + 4 * lh + 8 * q + t;
                        int iv   = tr * 128 + rowl;
                        float mn = mnA[rowl];
                        if (iv < size && jv < size && iv != jv && mn >= 0.f) {
                            float d2 = sqA[rowl] + sqj - 2.f * acc[g][h][q * 4 + t];
                            float dist = sqrtf(fmaxf(d2, 0.f));
                            tsum += fmaxf(dist - mn + MARGIN, 0.f);
                            tcnt += 1u;
                        }
                    }
            }
        }
    }

    #pragma unroll
    for (int off = 32; off > 0; off >>= 1) {
        tsum += __shfl_down(tsum, off);
        tcnt += __shfl_down(tcnt, off);
    }
    if (lane == 0) { sred[w] = (double)tsum; cred[w] = tcnt; }
    __syncthreads();
    if (tid == 0) {
        psum[c] = sred[0] + sred[1] + sred[2] + sred[3];
        pcnt[c] = cred[0] + cred[1] + cred[2] + cred[3];
    }
}

// ---------------------------------------------------------------------------
// Kernel 3: reduce 100 community partials -> final mean.
__global__ __launch_bounds__(256)
void finalize_kernel(const double* __restrict__ psum,
                     const unsigned int* __restrict__ pcnt,
                     float* __restrict__ out) {
    __shared__ double       ds[256];
    __shared__ unsigned int cs[256];
    const int t = threadIdx.x;
    double s = 0.0; unsigned int c = 0u;
    for (int b = t; b < N_COMM; b += 256) { s += psum[b]; c += pcnt[b]; }
    ds[t] = s; cs[t] = c;
    __syncthreads();
    for (int off = 128; off > 0; off >>= 1) {
        if (t < off) { ds[t] += ds[t + off]; cs[t] += cs[t + off]; }
        __syncthreads();
    }
    if (t == 0) out[0] = (cs[0] > 0u) ? (float)(ds[0] / (double)cs[0]) : 0.f;
}

// ---------------------------------------------------------------------------
extern "C" void kernel_launch(void* const* d_in, const int* in_sizes, int n_in,
                              void* d_out, int out_size, void* d_ws, size_t ws_size,
                              hipStream_t stream) {
    const float* x    = (const float*)d_in[0];
    const int*   comm = (const int*)d_in[1];
    float*       out  = (float*)d_out;

    // workspace layout (bytes):
    //       0 float  sq[8192]           32768
    //   32768 uint   min_d2[8192]       32768
    //   65536 int    offs[101]            512 (padded)
    //   66048 int    (unused)             512
    //   66560 int    members[8192]      32768
    //   99328 double psum[100]           1024 (padded)
    //  100352 uint   pcnt[100]            512 (padded)
    //  100864 ushort xhi[8192*128]    2097152
    // 2198016 ushort xlo[8192*128]    2097152   (total ~4.1 MB)
    char* ws = (char*)d_ws;
    float*          sq      = (float*)(ws);
    unsigned int*   min_d2  = (unsigned int*)(ws + 32768);
    int*            offs    = (int*)(ws + 65536);
    int*            members = (int*)(ws + 66560);
    double*         psum    = (double*)(ws + 99328);
    unsigned int*   pcnt    = (unsigned int*)(ws + 100352);
    unsigned short* xhi     = (unsigned short*)(ws + 100864);
    unsigned short* xlo     = (unsigned short*)(ws + 2198016);

    prep_kernel<<<2048 + N_COMM, 256, 0, stream>>>(x, comm, xhi, xlo, sq, min_d2,
                                                   offs, members);

    const int ntri = (N_NODES / 128) * (N_NODES / 128 + 1) / 2;   // 2080
    minneg_mfma_kernel<<<ntri, 256, 0, stream>>>(xhi, xlo, comm, sq, min_d2);

    pos_mfma_kernel<<<N_COMM, 256, 0, stream>>>(xhi, xlo, sq, min_d2, offs, members,
                                                psum, pcnt);

    finalize_kernel<<<1, 256, 0, stream>>>(psum, pcnt, out);
}